// Round 1
// baseline (62.828 us; speedup 1.0000x reference)
//
#include <hip/hip_runtime.h>

// MetaLSTM: per-param independent 16-step recurrence.
//   f_next = x·WF[0:20] + c*WF[20] + f*WF[21] + bF
//   i_next = x·WI[0:20] + c*WI[20] + i*WI[21] + bI
//   c_next = sigmoid(f_next)*c - sigmoid(i_next)*g[t]
// Outputs flat: [c (P), f (P), i (P)]
// Memory-bound: 320 MB x_all stream -> ~52 us floor at 6.3 TB/s.

#define T_STEPS 16
#define N_IN 20

__global__ __launch_bounds__(256) void metalstm_kernel(
    const float* __restrict__ x_all,  // [T, P, N]
    const float* __restrict__ grad,   // [T]
    const float* __restrict__ WF,     // [22]
    const float* __restrict__ WI,     // [22]
    const float* __restrict__ cI,     // [P]
    const float* __restrict__ bF,     // [1]
    const float* __restrict__ bI,     // [1]
    float* __restrict__ out,          // [3*P]
    int P)
{
    const int p = blockIdx.x * blockDim.x + threadIdx.x;
    if (p >= P) return;

    // Wave-uniform weights -> registers (all indices compile-time constant).
    float wF[22], wI[22];
#pragma unroll
    for (int k = 0; k < 22; ++k) { wF[k] = WF[k]; wI[k] = WI[k]; }
    const float biasF = bF[0];
    const float biasI = bI[0];

    float f = 0.0f;
    float ii = 0.0f;
    float c = cI[p];

#pragma unroll 2
    for (int t = 0; t < T_STEPS; ++t) {
        const float4* xp = reinterpret_cast<const float4*>(
            x_all + ((long)t * P + p) * N_IN);
        // 5 aligned float4 loads = the thread's 80-byte row for this step.
        const float4 v0 = xp[0];
        const float4 v1 = xp[1];
        const float4 v2 = xp[2];
        const float4 v3 = xp[3];
        const float4 v4 = xp[4];
        const float g_t = grad[t];  // uniform, L2-broadcast (avoids local array)

        float dF = biasF, dI = biasI;
#define ACC(val, k) dF = fmaf((val), wF[(k)], dF); dI = fmaf((val), wI[(k)], dI);
        ACC(v0.x, 0)  ACC(v0.y, 1)  ACC(v0.z, 2)  ACC(v0.w, 3)
        ACC(v1.x, 4)  ACC(v1.y, 5)  ACC(v1.z, 6)  ACC(v1.w, 7)
        ACC(v2.x, 8)  ACC(v2.y, 9)  ACC(v2.z, 10) ACC(v2.w, 11)
        ACC(v3.x, 12) ACC(v3.y, 13) ACC(v3.z, 14) ACC(v3.w, 15)
        ACC(v4.x, 16) ACC(v4.y, 17) ACC(v4.z, 18) ACC(v4.w, 19)
#undef ACC

        const float fn = fmaf(c, wF[20], fmaf(f, wF[21], dF));
        const float in_ = fmaf(c, wI[20], fmaf(ii, wI[21], dI));
        const float sf = 1.0f / (1.0f + expf(-fn));
        const float si = 1.0f / (1.0f + expf(-in_));
        c = sf * c - si * g_t;
        f = fn;
        ii = in_;
    }

    out[p]         = c;
    out[P + p]     = f;
    out[2 * P + p] = ii;
}

extern "C" void kernel_launch(void* const* d_in, const int* in_sizes, int n_in,
                              void* d_out, int out_size, void* d_ws, size_t ws_size,
                              hipStream_t stream) {
    const float* x_all = (const float*)d_in[0];
    const float* grad  = (const float*)d_in[1];
    const float* WF    = (const float*)d_in[2];
    const float* WI    = (const float*)d_in[3];
    const float* cI    = (const float*)d_in[4];
    const float* bF    = (const float*)d_in[5];
    const float* bI    = (const float*)d_in[6];
    float* out = (float*)d_out;

    const int P = in_sizes[4];
    const int block = 256;
    const int grid = (P + block - 1) / block;
    metalstm_kernel<<<grid, block, 0, stream>>>(x_all, grad, WF, WI, cI, bF, bI, out, P);
}

// Round 2
// 55.766 us; speedup vs baseline: 1.1266x; 1.1266x over previous
//
#include <hip/hip_runtime.h>

// MetaLSTM: per-param independent 16-step recurrence, memory-bound (320 MB x_all).
//   f_next = x·WF[0:20] + c*WF[20] + f*WF[21] + bF
//   i_next = x·WI[0:20] + c*WI[20] + i*WI[21] + bI
//   c_next = sigmoid(f_next)*c - sigmoid(i_next)*g[t]
// Outputs flat: [c (P), f (P), i (P)]
//
// R1: LDS-staged coalesced loads. Per step each block stages 256x20 floats
// with ideal lane-contiguous float4 loads (8 cache lines/load instead of 40),
// slot-rotated LDS layout keeps both ds_write_b128 and ds_read_b128
// conflict-free (<=2-way). Next-step slab prefetched to regs before barrier.

#define BLOCK 256
#define N_IN 20
#define ROW_F4 5  // float4 slots per row

__global__ __launch_bounds__(BLOCK) void metalstm_kernel(
    const float* __restrict__ x_all,  // [T, P, N]
    const float* __restrict__ grad,   // [T]
    const float* __restrict__ WF,     // [22]
    const float* __restrict__ WI,     // [22]
    const float* __restrict__ cI,     // [P]
    const float* __restrict__ bF,     // [1]
    const float* __restrict__ bI,     // [1]
    float* __restrict__ out,          // [3*P]
    int P, int T)
{
    __shared__ __align__(16) float4 xs4[BLOCK * ROW_F4];  // 20480 B

    const int tid = threadIdx.x;
    const int pbase = blockIdx.x * BLOCK;
    const int p = pbase + tid;
    const bool valid = (p < P);
    const int pc = valid ? p : (P - 1);

    // Wave-uniform weights -> scalar regs.
    float wF[22], wI[22];
#pragma unroll
    for (int k = 0; k < 22; ++k) { wF[k] = WF[k]; wI[k] = WI[k]; }
    const float biasF = bF[0];
    const float biasI = bI[0];

    float f = 0.0f;
    float ii = 0.0f;
    float c = cI[pc];

    const float4* __restrict__ x4 = reinterpret_cast<const float4*>(x_all);

    // Prefetch step 0 slab (coalesced: flat float4 index tid + k*BLOCK).
    float4 pr0, pr1, pr2, pr3, pr4;
    {
        const long base4 = (long)P * 0 * ROW_F4 + (long)pbase * ROW_F4;
        const long end4  = ((long)P * 0 + P) * ROW_F4;  // exclusive bound for step 0
#define LOADK(k, dst) { long idx = base4 + tid + (k) * BLOCK; \
                        if (idx >= end4) idx = end4 - 1; \
                        dst = x4[idx]; }
        LOADK(0, pr0) LOADK(1, pr1) LOADK(2, pr2) LOADK(3, pr3) LOADK(4, pr4)
    }

    for (int t = 0; t < T; ++t) {
        __syncthreads();  // previous step's LDS reads complete

        // Write prefetched slab to LDS, slot-rotated: orig slot s of row r
        // stored at slot (s + r) % 5.  (Permutation of 64 consecutive 16B
        // slots per wave-store -> conflict-free.)
#define STOREK(k, src) { const int fidx = tid + (k) * BLOCK; \
                         const int row = fidx / ROW_F4; \
                         const int sl  = fidx - row * ROW_F4; \
                         int slr = sl + row % ROW_F4; if (slr >= ROW_F4) slr -= ROW_F4; \
                         xs4[row * ROW_F4 + slr] = src; }
        STOREK(0, pr0) STOREK(1, pr1) STOREK(2, pr2) STOREK(3, pr3) STOREK(4, pr4)
#undef STOREK
        __syncthreads();  // slab visible

        // Prefetch next step's slab (overlaps with LDS reads + compute).
        if (t + 1 < T) {
            const long base4 = ((long)(t + 1) * P + pbase) * ROW_F4;
            const long end4  = ((long)(t + 1) * P + P) * ROW_F4;
            LOADK(0, pr0) LOADK(1, pr1) LOADK(2, pr2) LOADK(3, pr3) LOADK(4, pr4)
        }

        const float g_t = grad[t];

        // Read own row (rotated): reading slot (jj + tid) % 5 yields orig slot jj.
        float dF = biasF, dI = biasI;
        const int rbase = tid * ROW_F4;
        const int rrot  = tid % ROW_F4;
#define ACC4(jj) { int slr = (jj) + rrot; if (slr >= ROW_F4) slr -= ROW_F4; \
                   const float4 v = xs4[rbase + slr]; \
                   dF = fmaf(v.x, wF[4*(jj)+0], dF); dI = fmaf(v.x, wI[4*(jj)+0], dI); \
                   dF = fmaf(v.y, wF[4*(jj)+1], dF); dI = fmaf(v.y, wI[4*(jj)+1], dI); \
                   dF = fmaf(v.z, wF[4*(jj)+2], dF); dI = fmaf(v.z, wI[4*(jj)+2], dI); \
                   dF = fmaf(v.w, wF[4*(jj)+3], dF); dI = fmaf(v.w, wI[4*(jj)+3], dI); }
        ACC4(0) ACC4(1) ACC4(2) ACC4(3) ACC4(4)
#undef ACC4

        const float fn  = fmaf(c, wF[20], fmaf(f,  wF[21], dF));
        const float in_ = fmaf(c, wI[20], fmaf(ii, wI[21], dI));
        const float sf = 1.0f / (1.0f + __expf(-fn));
        const float si = 1.0f / (1.0f + __expf(-in_));
        c = sf * c - si * g_t;
        f = fn;
        ii = in_;
    }
#undef LOADK

    if (valid) {
        out[p]         = c;
        out[P + p]     = f;
        out[2 * P + p] = ii;
    }
}

extern "C" void kernel_launch(void* const* d_in, const int* in_sizes, int n_in,
                              void* d_out, int out_size, void* d_ws, size_t ws_size,
                              hipStream_t stream) {
    const float* x_all = (const float*)d_in[0];
    const float* grad  = (const float*)d_in[1];
    const float* WF    = (const float*)d_in[2];
    const float* WI    = (const float*)d_in[3];
    const float* cI    = (const float*)d_in[4];
    const float* bF    = (const float*)d_in[5];
    const float* bI    = (const float*)d_in[6];
    float* out = (float*)d_out;

    const int P = in_sizes[4];
    const int T = in_sizes[1];
    const int grid = (P + BLOCK - 1) / BLOCK;
    metalstm_kernel<<<grid, BLOCK, 0, stream>>>(x_all, grad, WF, WI, cI, bF, bI, out, P, T);
}